// Round 12
// baseline (194.331 us; speedup 1.0000x reference)
//
#include <hip/hip_runtime.h>
#include <hip/hip_bf16.h>

#define N_NODES_C  100000
#define N_EDGES_C  1600000
#define IN_FEATS_C 128
#define OUT_FEATS_C 32
#define NEG_SLOPE_C 0.2f

// src-sliced chains: edge e goes into chain slice src[e]>>SL_SHIFT of its dst.
// Gather walks slices in order -> the active slice's bf16 z rows (16384 x 64B
// = 1 MB) stay L2-resident on every XCD, cutting the z HBM stream ~90->~10MB.
#define SL_SHIFT 14
#define NSL      7        // ceil(100000 / 16384)

typedef __attribute__((ext_vector_type(8))) short short8;
typedef __attribute__((ext_vector_type(4))) float f32x4;

// Static device scratch (~23 MB) — no assumption about ws_size.
__device__ __hip_bfloat16 g_zb[N_NODES_C * OUT_FEATS_C];  // bf16 z: 64B/row
__device__ float  g_el[N_NODES_C];
__device__ float  g_er[N_NODES_C];
__device__ int    g_head[NSL][N_NODES_C];  // per-(src-slice, dst) chain heads
__device__ int2   g_ns[N_EDGES_C];         // packed {next, src} (coalesced store)
__device__ short8 g_wf_hi[2][4][64];       // W MFMA B-fragments (bf16 hi)
__device__ short8 g_wf_lo[2][4][64];       // ... lo part (hi+lo split ~ f32 accuracy)

static __device__ __forceinline__ unsigned short f2bf(float x) {
    unsigned int u = __float_as_uint(x);
    unsigned int r = (u + 0x7FFFu + ((u >> 16) & 1u)) >> 16;
    return (unsigned short)r;
}
static __device__ __forceinline__ float bf2f(unsigned short h) {
    return __uint_as_float(((unsigned int)h) << 16);
}

// ---------------- Kernel A: prep = head init + W fragment build ----------------
__global__ __launch_bounds__(256) void k_prep(const float* __restrict__ W, int nheads, int nbn)
{
    int b = blockIdx.x;
    if (b < nbn) {
        int i = b * 256 + threadIdx.x;
        if (i < nheads) ((int*)g_head)[i] = -1;   // re-init every call (stateless)
        return;
    }
    int i = (b - nbn) * 256 + threadIdx.x;        // 0..511
    if (i >= 512) return;
    int lane = i & 63;
    int kt   = (i >> 6) & 3;
    int nt   = i >> 8;
    int row  = nt * 16 + (lane & 15);
    const float* p = W + (size_t)row * IN_FEATS_C + kt * 32 + (lane >> 4) * 8;
    float4 x0 = *(const float4*)(p);
    float4 x1 = *(const float4*)(p + 4);
    float xs[8] = {x0.x, x0.y, x0.z, x0.w, x1.x, x1.y, x1.z, x1.w};
    short8 hi, lo;
#pragma unroll
    for (int j = 0; j < 8; ++j) {
        unsigned short hb = f2bf(xs[j]);
        hi[j] = (short)hb;
        lo[j] = (short)f2bf(xs[j] - bf2f(hb));
    }
    g_wf_hi[nt][kt][lane] = hi;
    g_wf_lo[nt][kt][lane] = lo;
}

// ---------------- Kernel B: FAT = MFMA projection ∪ sliced linked-list build ----
// Data-independent phases on different pipes, interleaved 1:4 by blockIdx
// (proven +24 µs in R11: co-resident populations overlap ~max, not sum).
__global__ __launch_bounds__(256) void k_fat(const float* __restrict__ h,
                                             const float* __restrict__ a,
                                             const int* __restrict__ src,
                                             const int* __restrict__ dst,
                                             int n_nodes, int n_edges,
                                             int PB, int LB)
{
    int bid = blockIdx.x;
    if (bid % 5 == 0) {
        // ---- project role: 4 tiles of 16 nodes per block ----
        int pidx = bid / 5;
        if (pidx >= PB) return;
        int tile = pidx * 4 + (threadIdx.x >> 6);
        int ntiles = (n_nodes + 15) / 16;
        if (tile >= ntiles) return;
        int l   = threadIdx.x & 63;
        int r16 = l & 15;
        int g   = l >> 4;

        const float* hrow = h + (size_t)(tile * 16 + r16) * IN_FEATS_C + g * 8;
        f32x4 acc0 = {0.f, 0.f, 0.f, 0.f};
        f32x4 acc1 = {0.f, 0.f, 0.f, 0.f};

#pragma unroll
        for (int kt = 0; kt < 4; ++kt) {
            float4 x0 = *(const float4*)(hrow + kt * 32);
            float4 x1 = *(const float4*)(hrow + kt * 32 + 4);
            float xs[8] = {x0.x, x0.y, x0.z, x0.w, x1.x, x1.y, x1.z, x1.w};
            short8 ahi, alo;
#pragma unroll
            for (int j = 0; j < 8; ++j) {
                unsigned short hb = f2bf(xs[j]);
                ahi[j] = (short)hb;
                alo[j] = (short)f2bf(xs[j] - bf2f(hb));
            }
            short8 bh0 = g_wf_hi[0][kt][l], bl0 = g_wf_lo[0][kt][l];
            short8 bh1 = g_wf_hi[1][kt][l], bl1 = g_wf_lo[1][kt][l];
            acc0 = __builtin_amdgcn_mfma_f32_16x16x32_bf16(ahi, bh0, acc0, 0, 0, 0);
            acc0 = __builtin_amdgcn_mfma_f32_16x16x32_bf16(alo, bh0, acc0, 0, 0, 0);
            acc0 = __builtin_amdgcn_mfma_f32_16x16x32_bf16(ahi, bl0, acc0, 0, 0, 0);
            acc1 = __builtin_amdgcn_mfma_f32_16x16x32_bf16(ahi, bh1, acc1, 0, 0, 0);
            acc1 = __builtin_amdgcn_mfma_f32_16x16x32_bf16(alo, bh1, acc1, 0, 0, 0);
            acc1 = __builtin_amdgcn_mfma_f32_16x16x32_bf16(ahi, bl1, acc1, 0, 0, 0);
        }

        float al0 = a[r16], al1 = a[16 + r16];
        float ar0 = a[32 + r16], ar1 = a[48 + r16];
        float elp[4], erp[4];
        unsigned short* zb = (unsigned short*)g_zb;
#pragma unroll
        for (int r = 0; r < 4; ++r) {
            float z0 = acc0[r], z1 = acc1[r];
            int node = tile * 16 + g * 4 + r;
            zb[(size_t)node * OUT_FEATS_C + r16]      = f2bf(z0);
            zb[(size_t)node * OUT_FEATS_C + 16 + r16] = f2bf(z1);
            elp[r] = z0 * al0 + z1 * al1;
            erp[r] = z0 * ar0 + z1 * ar1;
        }
#pragma unroll
        for (int m = 1; m <= 8; m <<= 1) {
#pragma unroll
            for (int r = 0; r < 4; ++r) {
                elp[r] += __shfl_xor(elp[r], m, 64);
                erp[r] += __shfl_xor(erp[r], m, 64);
            }
        }
        int nodeb = tile * 16 + g * 4;
        if (r16 == 0) {
#pragma unroll
            for (int r = 0; r < 4; ++r) g_el[nodeb + r] = elp[r];
        } else if (r16 == 1) {
#pragma unroll
            for (int r = 0; r < 4; ++r) g_er[nodeb + r] = erp[r];
        }
    } else {
        // ---- link role: 1 edge per thread, chain slice = src >> SL_SHIFT ----
        int lidx = 4 * (bid / 5) + (bid % 5) - 1;
        if (lidx >= LB) return;
        int e = lidx * 256 + threadIdx.x;
        if (e < n_edges) {
            int s  = src[e];
            int sl = s >> SL_SHIFT;
            int nxt = atomicExch(&g_head[sl][dst[e]], e);  // ONE random atomic/edge
            g_ns[e] = make_int2(nxt, s);                   // coalesced record store
        }
    }
}

// ---------------- Kernel C: gather via src-sliced chain sweep ----------------
// 32 lanes per node (lane = feature). Slices processed in order: the active
// slice's z rows (1 MB) stay L2-resident chip-wide, so the z stream stops
// missing to HBM. ns record stream (~102 MB random lines) is the remaining
// irreducible scattered traffic. Serial step count per node unchanged (16).
__global__ __launch_bounds__(256) void k_gather(float* __restrict__ out, int n_nodes)
{
    int tid  = blockIdx.x * blockDim.x + threadIdx.x;
    int node = tid >> 5;
    int f    = tid & 31;
    if (node >= n_nodes) return;

    int jj[NSL];
#pragma unroll
    for (int sl = 0; sl < NSL; ++sl) jj[sl] = g_head[sl][node];  // independent loads

    float er_d = g_er[node];
    const unsigned short* zb = (const unsigned short*)g_zb;
    float acc = 0.f, den = 0.f;

#pragma unroll
    for (int sl = 0; sl < NSL; ++sl) {
        int j = jj[sl];
        while (j >= 0) {
            int2 ns = g_ns[j];       // {next, src} in one line
            int s   = ns.y;
            float x = g_el[s] + er_d;
            x = (x > 0.f) ? x : NEG_SLOPE_C * x;
            float ex = __expf(x);    // shift-free softmax (logits O(5), safe in f32)
            den += ex;
            acc = fmaf(ex, bf2f(zb[(size_t)s * OUT_FEATS_C + f]), acc);  // L2-hot slice
            j = ns.x;
        }
    }
    out[(size_t)node * OUT_FEATS_C + f] = acc / fmaxf(den, 1e-16f);
}

extern "C" void kernel_launch(void* const* d_in, const int* in_sizes, int n_in,
                              void* d_out, int out_size, void* d_ws, size_t ws_size,
                              hipStream_t stream) {
    const float* h   = (const float*)d_in[0];
    const float* W   = (const float*)d_in[1];
    const float* a   = (const float*)d_in[2];
    const int*   src = (const int*)d_in[3];
    const int*   dst = (const int*)d_in[4];
    float* out = (float*)d_out;

    const int n_nodes = in_sizes[0] / IN_FEATS_C;   // 100000
    const int n_edges = in_sizes[3];                // 1600000

    const int nheads = NSL * n_nodes;
    const int nbn    = (nheads + 255) / 256;        // head-init blocks
    const int ntiles = (n_nodes + 15) / 16;         // 6250
    const int PB     = (ntiles + 3) / 4;            // 1563 project blocks
    const int LB     = (n_edges + 255) / 256;       // 6250 link blocks
    const int G      = 5 * ((PB > (LB + 3) / 4) ? PB : (LB + 3) / 4);

    // A) heads=-1 + W fragments
    k_prep<<<nbn + 2, 256, 0, stream>>>(W, nheads, nbn);
    // B) fat kernel: projection ∪ sliced linked-list build
    k_fat<<<G, 256, 0, stream>>>(h, a, src, dst, n_nodes, n_edges, PB, LB);
    // C) gather: src-sliced chain sweep (z slice L2-resident)
    k_gather<<<(n_nodes * 32 + 255) / 256, 256, 0, stream>>>(out, n_nodes);
}